// Round 3
// baseline (327.703 us; speedup 1.0000x reference)
//
#include <hip/hip_runtime.h>
#include <stdint.h>

#define BATCH 64
#define F_ENC 2048
#define HID 8192
#define NCLS 100
#define NMAT 6
#define NROWS (NMAT * HID)            // 49152 neuron rows total
#define CHUNK_VECS 16384              // uint4 per block chunk = 256 KB

typedef unsigned long long ull;

// ---------------------------------------------------------------------------
// Kernel 1: zero per-row nonzero counters + binarize/transpose-pack x.
// grid = 192 blocks x 256 = 49152 threads.
// ---------------------------------------------------------------------------
__global__ void __launch_bounds__(256) init_pack_kernel(
    const float* __restrict__ x, ull* __restrict__ A0,
    uint32_t* __restrict__ cnt) {
  int t = blockIdx.x * 256 + threadIdx.x;
  if (t < NROWS) cnt[t] = 0u;
  if (t < F_ENC) {
    ull m = 0;
#pragma unroll
    for (int b = 0; b < BATCH; ++b)
      m |= (ull)(x[(size_t)b * F_ENC + t] > 0.5f) << b;
    A0[t] = m;
  }
}

// ---------------------------------------------------------------------------
// Kernel 2: pure streaming sparsifier. One block per contiguous 256 KB chunk;
// no LDS, no barriers. Nonzeros (<=8 per row, ~0.1% of elements) get a slot
// from a global per-row atomic counter. Entry: uint16 = col | sign<<15.
// ---------------------------------------------------------------------------
__global__ void __launch_bounds__(256) sparsify_stream(
    const uint32_t* __restrict__ W0a, const uint32_t* __restrict__ W0b,
    const uint32_t* __restrict__ W1a, const uint32_t* __restrict__ W1b,
    const uint32_t* __restrict__ W2a, const uint32_t* __restrict__ W2b,
    uint16_t* __restrict__ entries, uint32_t* __restrict__ cnt) {
  int blk = blockIdx.x;
  int m, chunk, logCols;
  const uint32_t* Wbase;
  if (blk < 256)        { m = 0; Wbase = W0a; chunk = blk;        logCols = 11; }
  else if (blk < 512)   { m = 1; Wbase = W0b; chunk = blk - 256;  logCols = 11; }
  else if (blk < 1536)  { m = 2; Wbase = W1a; chunk = blk - 512;  logCols = 13; }
  else if (blk < 2560)  { m = 3; Wbase = W1b; chunk = blk - 1536; logCols = 13; }
  else if (blk < 3584)  { m = 4; Wbase = W2a; chunk = blk - 2560; logCols = 13; }
  else                  { m = 5; Wbase = W2b; chunk = blk - 3584; logCols = 13; }

  const uint4* V = (const uint4*)Wbase;
  const size_t vbase = (size_t)chunk * CHUNK_VECS;
  const uint32_t colMask = (1u << logCols) - 1u;
  const uint32_t rowBase = (uint32_t)m << 13;

  for (int it = 0; it < 16; ++it) {          // 16 iters x 4 vec4 x 256 thr
    uint4 w[4];
    uint32_t vi[4];
#pragma unroll
    for (int u = 0; u < 4; ++u) {            // all 4 loads issued together
      vi[u] = (uint32_t)(vbase + (size_t)(it * 4 + u) * 256 + threadIdx.x);
      w[u] = V[vi[u]];
    }
#pragma unroll
    for (int u = 0; u < 4; ++u) {
      uint4 ww = w[u];
      if (ww.x | ww.y | ww.z | ww.w) {       // rare
        uint32_t vals[4] = {ww.x, ww.y, ww.z, ww.w};
#pragma unroll
        for (int e = 0; e < 4; ++e) {
          uint32_t u32 = vals[e];
          if (u32 != 0u) {                   // exactly +1.0f or -1.0f
            uint32_t elem = (vi[u] << 2) + e;
            uint32_t r = rowBase + (elem >> logCols);
            uint32_t c = elem & colMask;
            uint32_t slot = atomicAdd(&cnt[r], 1u);  // slot < 8 guaranteed
            entries[(size_t)r * 8 + slot] =
                (uint16_t)(c | ((u32 >> 31) << 15));
          }
        }
      }
    }
  }
}

// ---------------------------------------------------------------------------
// Bit-sliced 4-bit counters over the 64-batch bitmask lanes.
// ---------------------------------------------------------------------------
struct BS4 { ull p0, p1, p2, p3; };

__device__ __forceinline__ void bs_add(BS4& a, ull m) {
  ull c = m, t;
  t = a.p0 ^ c; c &= a.p0; a.p0 = t;
  t = a.p1 ^ c; c &= a.p1; a.p1 = t;
  t = a.p2 ^ c; c &= a.p2; a.p2 = t;
  a.p3 ^= c;  // count <= 8, no overflow
}

// fired = (plus >= minus + 4), per batch bit
__device__ __forceinline__ ull bs_fired(const BS4& A, const BS4& Mn) {
  ull b0 = Mn.p0, b1 = Mn.p1;
  ull carry = Mn.p2;
  ull b2 = ~Mn.p2;
  ull b3 = Mn.p3 ^ carry;
  ull b4 = Mn.p3 & carry;
  ull res = 0, eq = ~0ull;
  eq &= ~b4;  // a4 == 0
  res |= eq & A.p3 & ~b3; eq &= ~(A.p3 ^ b3);
  res |= eq & A.p2 & ~b2; eq &= ~(A.p2 ^ b2);
  res |= eq & A.p1 & ~b1; eq &= ~(A.p1 ^ b1);
  res |= eq & A.p0 & ~b0; eq &= ~(A.p0 ^ b0);
  return res | eq;
}

// ---------------------------------------------------------------------------
// Kernel 3: one layer; entries as uint4, validity from counts, all 16
// gathers issued in parallel.
// ---------------------------------------------------------------------------
__global__ void __launch_bounds__(256) layer_kernel(
    const uint16_t* __restrict__ ent0, const uint16_t* __restrict__ ent1,
    const uint32_t* __restrict__ cnt0, const uint32_t* __restrict__ cnt1,
    const ull* __restrict__ Aprev, ull* __restrict__ Anext) {
  int h = blockIdx.x * blockDim.x + threadIdx.x;
  if (h >= HID) return;
  uint4 p0 = ((const uint4*)ent0)[h];
  uint4 p1 = ((const uint4*)ent1)[h];
  uint32_t c0 = cnt0[h], c1 = cnt1[h];
  uint32_t wd[8] = {p0.x, p0.y, p0.z, p0.w, p1.x, p1.y, p1.z, p1.w};
  uint16_t es[16];
  bool valid[16];
#pragma unroll
  for (int i = 0; i < 8; ++i) {
    es[2 * i]     = (uint16_t)(wd[i] & 0xFFFFu);
    es[2 * i + 1] = (uint16_t)(wd[i] >> 16);
  }
#pragma unroll
  for (int i = 0; i < 16; ++i)
    valid[i] = (i < 8) ? ((uint32_t)i < c0) : ((uint32_t)(i - 8) < c1);
  ull M[16];
#pragma unroll
  for (int i = 0; i < 16; ++i) {
    int idx = valid[i] ? (es[i] & 0x1FFF) : 0;
    ull v = Aprev[idx];
    M[i] = valid[i] ? v : 0ull;
  }
  ull f = 0;
#pragma unroll
  for (int s = 0; s < 2; ++s) {
    BS4 P{0, 0, 0, 0}, N{0, 0, 0, 0};
#pragma unroll
    for (int i = 0; i < 8; ++i) {
      uint16_t e = es[s * 8 + i];
      ull Mm = M[s * 8 + i];
      ull mp = (e & 0x8000) ? 0ull : Mm;
      ull mn = (e & 0x8000) ? Mm : 0ull;
      bs_add(P, mp);
      bs_add(N, mn);
    }
    f |= bs_fired(P, N);
  }
  Anext[h] = f;
}

// ---------------------------------------------------------------------------
// Kernel 4a: per-block partial logits into ws. 4b: reduce into d_out.
// ---------------------------------------------------------------------------
__global__ void __launch_bounds__(128) logits_partial(
    const ull* __restrict__ A1, const ull* __restrict__ A2,
    const ull* __restrict__ A3,
    const float* __restrict__ O0, const float* __restrict__ O1,
    const float* __restrict__ O2, float* __restrict__ part, int rows) {
  __shared__ float acc[BATCH * NCLS];  // 25.6 KB
  for (int i = threadIdx.x; i < BATCH * NCLS; i += 128) acc[i] = 0.f;
  __syncthreads();
  const int j = threadIdx.x;
  const int h0 = blockIdx.x * rows;
  if (j < NCLS) {
    for (int k = 0; k < rows; ++k) {
      int h = h0 + k;
      ull m;
      m = A1[h];
      if (m) {
        float o = O0[(size_t)h * NCLS + j];
        do { int b = __builtin_ctzll(m); m &= m - 1; acc[b * NCLS + j] += o; } while (m);
      }
      m = A2[h];
      if (m) {
        float o = O1[(size_t)h * NCLS + j];
        do { int b = __builtin_ctzll(m); m &= m - 1; acc[b * NCLS + j] += o; } while (m);
      }
      m = A3[h];
      if (m) {
        float o = O2[(size_t)h * NCLS + j];
        do { int b = __builtin_ctzll(m); m &= m - 1; acc[b * NCLS + j] += o; } while (m);
      }
    }
  }
  __syncthreads();
  float* dst = part + (size_t)blockIdx.x * (BATCH * NCLS);
  for (int i = threadIdx.x; i < BATCH * NCLS; i += 128) dst[i] = acc[i];
}

__global__ void logits_reduce(const float* __restrict__ part,
                              float* __restrict__ out, int nb) {
  int i = blockIdx.x * 256 + threadIdx.x;
  if (i >= BATCH * NCLS) return;
  float s = 0.f;
  for (int b = 0; b < nb; ++b) s += part[(size_t)b * (BATCH * NCLS) + i];
  out[i] = s;
}

// ---------------------------------------------------------------------------
extern "C" void kernel_launch(void* const* d_in, const int* in_sizes, int n_in,
                              void* d_out, int out_size, void* d_ws, size_t ws_size,
                              hipStream_t stream) {
  const float*    x   = (const float*)d_in[0];
  const uint32_t* W0a = (const uint32_t*)d_in[1];
  const uint32_t* W0b = (const uint32_t*)d_in[2];
  const uint32_t* W1a = (const uint32_t*)d_in[3];
  const uint32_t* W1b = (const uint32_t*)d_in[4];
  const uint32_t* W2a = (const uint32_t*)d_in[5];
  const uint32_t* W2b = (const uint32_t*)d_in[6];
  const float*    O0  = (const float*)d_in[7];
  const float*    O1  = (const float*)d_in[8];
  const float*    O2  = (const float*)d_in[9];
  float* out = (float*)d_out;
  char*  ws  = (char*)d_ws;

  // ws layout (everything read is written earlier in the same call):
  ull* A0 = (ull*)(ws);                              // 16384 B
  ull* A1 = (ull*)(ws + 16384);                      // 65536 B
  ull* A2 = (ull*)(ws + 16384 + 65536);
  ull* A3 = (ull*)(ws + 16384 + 2 * 65536);
  uint16_t* entries = (uint16_t*)(ws + 16384 + 3 * 65536);   // 786432 B
  uint32_t* cnt = (uint32_t*)(ws + 16384 + 3 * 65536 + 786432); // 196608 B
  size_t base = 16384 + 3 * 65536 + 786432 + 196608;          // 1196032
  float* part = (float*)(ws + base);

  size_t avail = (ws_size > base) ? (ws_size - base) : 0;
  int NB = 128;
  while (NB > 1 && (size_t)NB * (BATCH * NCLS * 4) > avail) NB >>= 1;
  int rows = HID / NB;

  init_pack_kernel<<<192, 256, 0, stream>>>(x, A0, cnt);
  sparsify_stream<<<4608, 256, 0, stream>>>(W0a, W0b, W1a, W1b, W2a, W2b,
                                            entries, cnt);
  layer_kernel<<<HID / 256, 256, 0, stream>>>(
      entries + (size_t)0 * HID * 8, entries + (size_t)1 * HID * 8,
      cnt + 0 * HID, cnt + 1 * HID, A0, A1);
  layer_kernel<<<HID / 256, 256, 0, stream>>>(
      entries + (size_t)2 * HID * 8, entries + (size_t)3 * HID * 8,
      cnt + 2 * HID, cnt + 3 * HID, A1, A2);
  layer_kernel<<<HID / 256, 256, 0, stream>>>(
      entries + (size_t)4 * HID * 8, entries + (size_t)5 * HID * 8,
      cnt + 4 * HID, cnt + 5 * HID, A2, A3);
  logits_partial<<<NB, 128, 0, stream>>>(A1, A2, A3, O0, O1, O2, part, rows);
  logits_reduce<<<(BATCH * NCLS + 255) / 256, 256, 0, stream>>>(part, out, NB);
}

// Round 4
// 271.413 us; speedup vs baseline: 1.2074x; 1.2074x over previous
//
#include <hip/hip_runtime.h>
#include <stdint.h>

#define BATCH 64
#define F_ENC 2048
#define HID 8192
#define NCLS 100
#define NMAT 6

typedef unsigned long long ull;
typedef uint32_t u32x4 __attribute__((ext_vector_type(4)));

// ---------------------------------------------------------------------------
// Kernel 1: binarize x and transpose-pack into per-column 64-bit batch masks.
// ---------------------------------------------------------------------------
__global__ void pack_kernel(const float* __restrict__ x, ull* __restrict__ A0) {
  int c = blockIdx.x * blockDim.x + threadIdx.x;  // 2048 threads total
  if (c < F_ENC) {
    ull m = 0;
#pragma unroll
    for (int b = 0; b < BATCH; ++b)
      m |= (ull)(x[(size_t)b * F_ENC + c] > 0.5f) << b;
    A0[c] = m;
  }
}

// ---------------------------------------------------------------------------
// Kernel 2: stream every W matrix (1.21 GB) with NON-TEMPORAL loads (evict-
// early, no L2/L3 thrash) and extract the <=8 nonzero (col,sign) entries per
// row. One block per row. All of a thread's loads are forced to be in flight
// together by OR-consuming every loaded register before any branch.
// Entry: uint16 = col (13b) | sign<<15. 0xFFFF = empty.
// ---------------------------------------------------------------------------
__device__ __forceinline__ void scan_vec(u32x4 w, int vecIdx,
                                         unsigned* s_cnt, uint16_t* s_ent) {
  uint32_t vals[4] = {w[0], w[1], w[2], w[3]};
#pragma unroll
  for (int e = 0; e < 4; ++e) {
    uint32_t u = vals[e];
    if (u != 0u) {  // value is exactly +1.0f or -1.0f
      unsigned slot = atomicAdd(s_cnt, 1u);
      s_ent[slot & 15u] = (uint16_t)(((vecIdx << 2) + e) | ((u >> 31) << 15));
    }
  }
}

__global__ void __launch_bounds__(256) sparsify_kernel(
    const uint32_t* __restrict__ W0a, const uint32_t* __restrict__ W0b,
    const uint32_t* __restrict__ W1a, const uint32_t* __restrict__ W1b,
    const uint32_t* __restrict__ W2a, const uint32_t* __restrict__ W2b,
    uint16_t* __restrict__ entries) {
  int m = blockIdx.x >> 13;          // which matrix (0..5)
  int r = blockIdx.x & (HID - 1);    // row within matrix
  const uint32_t* Wbase;
  switch (m) {
    case 0: Wbase = W0a; break;
    case 1: Wbase = W0b; break;
    case 2: Wbase = W1a; break;
    case 3: Wbase = W1b; break;
    case 4: Wbase = W2a; break;
    default: Wbase = W2b; break;
  }
  const int cols = (m < 2) ? F_ENC : HID;
  const u32x4* row = (const u32x4*)(Wbase + (size_t)r * cols);

  __shared__ unsigned s_cnt;
  __shared__ uint16_t s_ent[16];
  if (threadIdx.x == 0) s_cnt = 0u;
  __syncthreads();

  if (cols == F_ENC) {  // 2 x dwordx4 per thread, both in flight
    u32x4 w0 = __builtin_nontemporal_load(row + threadIdx.x);
    u32x4 w1 = __builtin_nontemporal_load(row + threadIdx.x + 256);
    uint32_t any = w0[0] | w0[1] | w0[2] | w0[3] |
                   w1[0] | w1[1] | w1[2] | w1[3];
    if (any) {  // rare (~0.8% of threads)
      scan_vec(w0, threadIdx.x, &s_cnt, s_ent);
      scan_vec(w1, threadIdx.x + 256, &s_cnt, s_ent);
    }
  } else {  // 8 x dwordx4 per thread: whole 32KB row in flight at once
    u32x4 w[8];
#pragma unroll
    for (int e = 0; e < 8; ++e)
      w[e] = __builtin_nontemporal_load(row + threadIdx.x + (e << 8));
    uint32_t any = 0;
#pragma unroll
    for (int e = 0; e < 8; ++e) any |= w[e][0] | w[e][1] | w[e][2] | w[e][3];
    if (any) {  // rare (~0.4% of threads)
#pragma unroll
      for (int e = 0; e < 8; ++e)
        scan_vec(w[e], threadIdx.x + (e << 8), &s_cnt, s_ent);
    }
  }
  __syncthreads();
  if (threadIdx.x < 8) {
    unsigned cnt = s_cnt;
    uint16_t v = (threadIdx.x < cnt) ? s_ent[threadIdx.x] : (uint16_t)0xFFFF;
    entries[(size_t)blockIdx.x * 8 + threadIdx.x] = v;
  }
}

// ---------------------------------------------------------------------------
// Bit-sliced 4-bit counters over the 64-batch bitmask lanes.
// ---------------------------------------------------------------------------
struct BS4 { ull p0, p1, p2, p3; };

__device__ __forceinline__ void bs_add(BS4& a, ull m) {
  ull c = m, t;
  t = a.p0 ^ c; c &= a.p0; a.p0 = t;
  t = a.p1 ^ c; c &= a.p1; a.p1 = t;
  t = a.p2 ^ c; c &= a.p2; a.p2 = t;
  a.p3 ^= c;  // count <= 8, no overflow
}

// fired = (plus >= minus + 4), per batch bit
__device__ __forceinline__ ull bs_fired(const BS4& A, const BS4& Mn) {
  ull b0 = Mn.p0, b1 = Mn.p1;
  ull carry = Mn.p2;
  ull b2 = ~Mn.p2;
  ull b3 = Mn.p3 ^ carry;
  ull b4 = Mn.p3 & carry;
  ull res = 0, eq = ~0ull;
  eq &= ~b4;  // a4 == 0
  res |= eq & A.p3 & ~b3; eq &= ~(A.p3 ^ b3);
  res |= eq & A.p2 & ~b2; eq &= ~(A.p2 ^ b2);
  res |= eq & A.p1 & ~b1; eq &= ~(A.p1 ^ b1);
  res |= eq & A.p0 & ~b0; eq &= ~(A.p0 ^ b0);
  return res | eq;
}

// ---------------------------------------------------------------------------
// Kernel 3: one layer. Entries loaded as one uint4 per segment; all 16
// Aprev gathers issued in parallel.
// ---------------------------------------------------------------------------
__global__ void __launch_bounds__(256) layer_kernel(
    const uint16_t* __restrict__ ent0, const uint16_t* __restrict__ ent1,
    const ull* __restrict__ Aprev, ull* __restrict__ Anext) {
  int h = blockIdx.x * blockDim.x + threadIdx.x;
  if (h >= HID) return;
  uint4 p0 = ((const uint4*)ent0)[h];
  uint4 p1 = ((const uint4*)ent1)[h];
  uint32_t wd[8] = {p0.x, p0.y, p0.z, p0.w, p1.x, p1.y, p1.z, p1.w};
  uint16_t es[16];
#pragma unroll
  for (int i = 0; i < 8; ++i) {
    es[2 * i]     = (uint16_t)(wd[i] & 0xFFFFu);
    es[2 * i + 1] = (uint16_t)(wd[i] >> 16);
  }
  ull M[16];
#pragma unroll
  for (int i = 0; i < 16; ++i) {
    int idx = (es[i] == 0xFFFF) ? 0 : (es[i] & 0x1FFF);
    ull v = Aprev[idx];
    M[i] = (es[i] == 0xFFFF) ? 0ull : v;
  }
  ull f = 0;
#pragma unroll
  for (int s = 0; s < 2; ++s) {
    BS4 P{0, 0, 0, 0}, N{0, 0, 0, 0};
#pragma unroll
    for (int i = 0; i < 8; ++i) {
      uint16_t e = es[s * 8 + i];
      ull Mm = M[s * 8 + i];
      ull mp = (e & 0x8000) ? 0ull : Mm;
      ull mn = (e & 0x8000) ? Mm : 0ull;
      bs_add(P, mp);
      bs_add(N, mn);
    }
    f |= bs_fired(P, N);
  }
  Anext[h] = f;
}

// ---------------------------------------------------------------------------
// Kernel 4a: per-block partial logits into ws. 4b: reduce into d_out.
// ---------------------------------------------------------------------------
__global__ void __launch_bounds__(128) logits_partial(
    const ull* __restrict__ A1, const ull* __restrict__ A2,
    const ull* __restrict__ A3,
    const float* __restrict__ O0, const float* __restrict__ O1,
    const float* __restrict__ O2, float* __restrict__ part, int rows) {
  __shared__ float acc[BATCH * NCLS];  // 25.6 KB
  for (int i = threadIdx.x; i < BATCH * NCLS; i += 128) acc[i] = 0.f;
  __syncthreads();
  const int j = threadIdx.x;
  const int h0 = blockIdx.x * rows;
  if (j < NCLS) {
    for (int k = 0; k < rows; ++k) {
      int h = h0 + k;
      ull m;
      m = A1[h];
      if (m) {
        float o = O0[(size_t)h * NCLS + j];
        do { int b = __builtin_ctzll(m); m &= m - 1; acc[b * NCLS + j] += o; } while (m);
      }
      m = A2[h];
      if (m) {
        float o = O1[(size_t)h * NCLS + j];
        do { int b = __builtin_ctzll(m); m &= m - 1; acc[b * NCLS + j] += o; } while (m);
      }
      m = A3[h];
      if (m) {
        float o = O2[(size_t)h * NCLS + j];
        do { int b = __builtin_ctzll(m); m &= m - 1; acc[b * NCLS + j] += o; } while (m);
      }
    }
  }
  __syncthreads();
  float* dst = part + (size_t)blockIdx.x * (BATCH * NCLS);
  for (int i = threadIdx.x; i < BATCH * NCLS; i += 128) dst[i] = acc[i];
}

__global__ void logits_reduce(const float* __restrict__ part,
                              float* __restrict__ out, int nb) {
  int i = blockIdx.x * 256 + threadIdx.x;
  if (i >= BATCH * NCLS) return;
  float s = 0.f;
  for (int b = 0; b < nb; ++b) s += part[(size_t)b * (BATCH * NCLS) + i];
  out[i] = s;
}

// ---------------------------------------------------------------------------
extern "C" void kernel_launch(void* const* d_in, const int* in_sizes, int n_in,
                              void* d_out, int out_size, void* d_ws, size_t ws_size,
                              hipStream_t stream) {
  const float*    x   = (const float*)d_in[0];
  const uint32_t* W0a = (const uint32_t*)d_in[1];
  const uint32_t* W0b = (const uint32_t*)d_in[2];
  const uint32_t* W1a = (const uint32_t*)d_in[3];
  const uint32_t* W1b = (const uint32_t*)d_in[4];
  const uint32_t* W2a = (const uint32_t*)d_in[5];
  const uint32_t* W2b = (const uint32_t*)d_in[6];
  const float*    O0  = (const float*)d_in[7];
  const float*    O1  = (const float*)d_in[8];
  const float*    O2  = (const float*)d_in[9];
  float* out = (float*)d_out;
  char*  ws  = (char*)d_ws;

  // ws layout (all written before read every call):
  ull* A0 = (ull*)(ws);                          // 2048*8   = 16384 B
  ull* A1 = (ull*)(ws + 16384);                  // 8192*8   = 65536 B
  ull* A2 = (ull*)(ws + 16384 + 65536);
  ull* A3 = (ull*)(ws + 16384 + 2 * 65536);
  uint16_t* entries = (uint16_t*)(ws + 16384 + 3 * 65536);  // 786432 B
  size_t base = 16384 + 3 * 65536 + 786432;                 // = 999424
  float* part = (float*)(ws + base);

  // choose #partial blocks by available ws (each needs 25600 B)
  size_t avail = (ws_size > base) ? (ws_size - base) : 0;
  int NB = 128;
  while (NB > 1 && (size_t)NB * (BATCH * NCLS * 4) > avail) NB >>= 1;
  int rows = HID / NB;

  pack_kernel<<<8, 256, 0, stream>>>(x, A0);
  sparsify_kernel<<<NMAT * HID, 256, 0, stream>>>(W0a, W0b, W1a, W1b, W2a, W2b,
                                                  entries);
  layer_kernel<<<HID / 256, 256, 0, stream>>>(
      entries + (size_t)0 * HID * 8, entries + (size_t)1 * HID * 8, A0, A1);
  layer_kernel<<<HID / 256, 256, 0, stream>>>(
      entries + (size_t)2 * HID * 8, entries + (size_t)3 * HID * 8, A1, A2);
  layer_kernel<<<HID / 256, 256, 0, stream>>>(
      entries + (size_t)4 * HID * 8, entries + (size_t)5 * HID * 8, A2, A3);
  logits_partial<<<NB, 128, 0, stream>>>(A1, A2, A3, O0, O1, O2, part, rows);
  logits_reduce<<<(BATCH * NCLS + 255) / 256, 256, 0, stream>>>(part, out, NB);
}

// Round 5
// 226.166 us; speedup vs baseline: 1.4489x; 1.2001x over previous
//
#include <hip/hip_runtime.h>
#include <stdint.h>

#define BATCH 64
#define F_ENC 2048
#define HID 8192
#define NCLS 100
#define NMAT 6

typedef unsigned long long ull;
typedef uint32_t u32x4 __attribute__((ext_vector_type(4)));

// ---------------------------------------------------------------------------
// Kernel 1: binarize x -> per-column 64-bit batch masks; also zero d_out.
// ---------------------------------------------------------------------------
__global__ void pack_kernel(const float* __restrict__ x, ull* __restrict__ A0,
                            float* __restrict__ out) {
  int c = blockIdx.x * blockDim.x + threadIdx.x;  // 2048 threads total
  for (int i = c; i < BATCH * NCLS; i += F_ENC) out[i] = 0.f;
  if (c < F_ENC) {
    ull m = 0;
#pragma unroll
    for (int b = 0; b < BATCH; ++b)
      m |= (ull)(x[(size_t)b * F_ENC + c] > 0.5f) << b;
    A0[c] = m;
  }
}

// ---------------------------------------------------------------------------
// Kernel 2: stream every W matrix (1.21 GB) with NON-TEMPORAL loads and a
// hard asm memory-clobber between load batch and consumption, so all of a
// thread's loads are genuinely in flight together (32 dest VGPRs).
// One block per row. Entry: uint16 = col (13b) | sign<<15. 0xFFFF = empty.
// ---------------------------------------------------------------------------
__device__ __forceinline__ void scan_vec(u32x4 w, int vecIdx,
                                         unsigned* s_cnt, uint16_t* s_ent) {
  uint32_t vals[4] = {w[0], w[1], w[2], w[3]};
#pragma unroll
  for (int e = 0; e < 4; ++e) {
    uint32_t u = vals[e];
    if (u != 0u) {  // value is exactly +1.0f or -1.0f
      unsigned slot = atomicAdd(s_cnt, 1u);
      s_ent[slot & 15u] = (uint16_t)(((vecIdx << 2) + e) | ((u >> 31) << 15));
    }
  }
}

__global__ void __launch_bounds__(256) sparsify_kernel(
    const uint32_t* __restrict__ W0a, const uint32_t* __restrict__ W0b,
    const uint32_t* __restrict__ W1a, const uint32_t* __restrict__ W1b,
    const uint32_t* __restrict__ W2a, const uint32_t* __restrict__ W2b,
    uint16_t* __restrict__ entries) {
  int m = blockIdx.x >> 13;          // which matrix (0..5)
  int r = blockIdx.x & (HID - 1);    // row within matrix
  const uint32_t* Wbase;
  switch (m) {
    case 0: Wbase = W0a; break;
    case 1: Wbase = W0b; break;
    case 2: Wbase = W1a; break;
    case 3: Wbase = W1b; break;
    case 4: Wbase = W2a; break;
    default: Wbase = W2b; break;
  }
  const int cols = (m < 2) ? F_ENC : HID;
  const u32x4* row = (const u32x4*)(Wbase + (size_t)r * cols);

  __shared__ unsigned s_cnt;
  __shared__ uint16_t s_ent[16];
  if (threadIdx.x == 0) s_cnt = 0u;
  __syncthreads();

  if (cols == F_ENC) {  // 2 x dwordx4 per thread, both in flight
    u32x4 w0 = __builtin_nontemporal_load(row + threadIdx.x);
    u32x4 w1 = __builtin_nontemporal_load(row + threadIdx.x + 256);
    asm volatile("" ::: "memory");  // loads may not sink past this
    uint32_t any = w0[0] | w0[1] | w0[2] | w0[3] |
                   w1[0] | w1[1] | w1[2] | w1[3];
    if (any) {  // rare (~0.8% of threads)
      scan_vec(w0, threadIdx.x, &s_cnt, s_ent);
      scan_vec(w1, threadIdx.x + 256, &s_cnt, s_ent);
    }
  } else {  // 8 x dwordx4 per thread: whole 32KB row in flight at once
    u32x4 w[8];
#pragma unroll
    for (int e = 0; e < 8; ++e)
      w[e] = __builtin_nontemporal_load(row + threadIdx.x + (e << 8));
    asm volatile("" ::: "memory");  // force all 8 issued before any consume
    uint32_t any = 0;
#pragma unroll
    for (int e = 0; e < 8; ++e) any |= w[e][0] | w[e][1] | w[e][2] | w[e][3];
    if (any) {  // rare (~0.4% of threads)
#pragma unroll
      for (int e = 0; e < 8; ++e)
        scan_vec(w[e], threadIdx.x + (e << 8), &s_cnt, s_ent);
    }
  }
  __syncthreads();
  if (threadIdx.x < 8) {
    unsigned cnt = s_cnt;
    uint16_t v = (threadIdx.x < cnt) ? s_ent[threadIdx.x] : (uint16_t)0xFFFF;
    entries[(size_t)blockIdx.x * 8 + threadIdx.x] = v;
  }
}

// ---------------------------------------------------------------------------
// Bit-sliced 4-bit counters over the 64-batch bitmask lanes.
// ---------------------------------------------------------------------------
struct BS4 { ull p0, p1, p2, p3; };

__device__ __forceinline__ void bs_add(BS4& a, ull m) {
  ull c = m, t;
  t = a.p0 ^ c; c &= a.p0; a.p0 = t;
  t = a.p1 ^ c; c &= a.p1; a.p1 = t;
  t = a.p2 ^ c; c &= a.p2; a.p2 = t;
  a.p3 ^= c;  // count <= 8, no overflow
}

// fired = (plus >= minus + 4), per batch bit
__device__ __forceinline__ ull bs_fired(const BS4& A, const BS4& Mn) {
  ull b0 = Mn.p0, b1 = Mn.p1;
  ull carry = Mn.p2;
  ull b2 = ~Mn.p2;
  ull b3 = Mn.p3 ^ carry;
  ull b4 = Mn.p3 & carry;
  ull res = 0, eq = ~0ull;
  eq &= ~b4;  // a4 == 0
  res |= eq & A.p3 & ~b3; eq &= ~(A.p3 ^ b3);
  res |= eq & A.p2 & ~b2; eq &= ~(A.p2 ^ b2);
  res |= eq & A.p1 & ~b1; eq &= ~(A.p1 ^ b1);
  res |= eq & A.p0 & ~b0; eq &= ~(A.p0 ^ b0);
  return res | eq;
}

// ---------------------------------------------------------------------------
// Kernel 3: one layer. Entries loaded as one uint4 per segment; all 16
// Aprev gathers issued in parallel.
// ---------------------------------------------------------------------------
__global__ void __launch_bounds__(256) layer_kernel(
    const uint16_t* __restrict__ ent0, const uint16_t* __restrict__ ent1,
    const ull* __restrict__ Aprev, ull* __restrict__ Anext) {
  int h = blockIdx.x * blockDim.x + threadIdx.x;
  if (h >= HID) return;
  uint4 p0 = ((const uint4*)ent0)[h];
  uint4 p1 = ((const uint4*)ent1)[h];
  uint32_t wd[8] = {p0.x, p0.y, p0.z, p0.w, p1.x, p1.y, p1.z, p1.w};
  uint16_t es[16];
#pragma unroll
  for (int i = 0; i < 8; ++i) {
    es[2 * i]     = (uint16_t)(wd[i] & 0xFFFFu);
    es[2 * i + 1] = (uint16_t)(wd[i] >> 16);
  }
  ull M[16];
#pragma unroll
  for (int i = 0; i < 16; ++i) {
    int idx = (es[i] == 0xFFFF) ? 0 : (es[i] & 0x1FFF);
    ull v = Aprev[idx];
    M[i] = (es[i] == 0xFFFF) ? 0ull : v;
  }
  ull f = 0;
#pragma unroll
  for (int s = 0; s < 2; ++s) {
    BS4 P{0, 0, 0, 0}, N{0, 0, 0, 0};
#pragma unroll
    for (int i = 0; i < 8; ++i) {
      uint16_t e = es[s * 8 + i];
      ull Mm = M[s * 8 + i];
      ull mp = (e & 0x8000) ? 0ull : Mm;
      ull mn = (e & 0x8000) ? Mm : 0ull;
      bs_add(P, mp);
      bs_add(N, mn);
    }
    f |= bs_fired(P, N);
  }
  Anext[h] = f;
}

// ---------------------------------------------------------------------------
// Kernel 4: logits. 256 blocks x 32 rows; LDS accumulate per block, then one
// atomicAdd pass into d_out (zeroed by pack_kernel). ws-independent.
// Masks for all 3 matrices are loaded up-front per row (shorter dep chain).
// ---------------------------------------------------------------------------
__global__ void __launch_bounds__(128) logits_kernel(
    const ull* __restrict__ A1, const ull* __restrict__ A2,
    const ull* __restrict__ A3,
    const float* __restrict__ O0, const float* __restrict__ O1,
    const float* __restrict__ O2, float* __restrict__ out) {
  __shared__ float acc[BATCH * NCLS];  // 25.6 KB
  for (int i = threadIdx.x; i < BATCH * NCLS; i += 128) acc[i] = 0.f;
  __syncthreads();
  const int j = threadIdx.x;
  const int h0 = blockIdx.x * 32;
  if (j < NCLS) {
    for (int k = 0; k < 32; ++k) {
      int h = h0 + k;
      ull m1 = A1[h], m2 = A2[h], m3 = A3[h];  // independent loads first
      if (m1) {
        float o = O0[(size_t)h * NCLS + j];
        do { int b = __builtin_ctzll(m1); m1 &= m1 - 1; acc[b * NCLS + j] += o; } while (m1);
      }
      if (m2) {
        float o = O1[(size_t)h * NCLS + j];
        do { int b = __builtin_ctzll(m2); m2 &= m2 - 1; acc[b * NCLS + j] += o; } while (m2);
      }
      if (m3) {
        float o = O2[(size_t)h * NCLS + j];
        do { int b = __builtin_ctzll(m3); m3 &= m3 - 1; acc[b * NCLS + j] += o; } while (m3);
      }
    }
  }
  __syncthreads();
  for (int i = threadIdx.x; i < BATCH * NCLS; i += 128)
    atomicAdd(&out[i], acc[i]);
}

// ---------------------------------------------------------------------------
extern "C" void kernel_launch(void* const* d_in, const int* in_sizes, int n_in,
                              void* d_out, int out_size, void* d_ws, size_t ws_size,
                              hipStream_t stream) {
  const float*    x   = (const float*)d_in[0];
  const uint32_t* W0a = (const uint32_t*)d_in[1];
  const uint32_t* W0b = (const uint32_t*)d_in[2];
  const uint32_t* W1a = (const uint32_t*)d_in[3];
  const uint32_t* W1b = (const uint32_t*)d_in[4];
  const uint32_t* W2a = (const uint32_t*)d_in[5];
  const uint32_t* W2b = (const uint32_t*)d_in[6];
  const float*    O0  = (const float*)d_in[7];
  const float*    O1  = (const float*)d_in[8];
  const float*    O2  = (const float*)d_in[9];
  float* out = (float*)d_out;
  char*  ws  = (char*)d_ws;

  // ws layout (all written before read every call; <1 MB total):
  ull* A0 = (ull*)(ws);                          // 2048*8   = 16384 B
  ull* A1 = (ull*)(ws + 16384);                  // 8192*8   = 65536 B
  ull* A2 = (ull*)(ws + 16384 + 65536);
  ull* A3 = (ull*)(ws + 16384 + 2 * 65536);
  uint16_t* entries = (uint16_t*)(ws + 16384 + 3 * 65536);  // 786432 B

  pack_kernel<<<8, 256, 0, stream>>>(x, A0, out);
  sparsify_kernel<<<NMAT * HID, 256, 0, stream>>>(W0a, W0b, W1a, W1b, W2a, W2b,
                                                  entries);
  layer_kernel<<<HID / 256, 256, 0, stream>>>(
      entries + (size_t)0 * HID * 8, entries + (size_t)1 * HID * 8, A0, A1);
  layer_kernel<<<HID / 256, 256, 0, stream>>>(
      entries + (size_t)2 * HID * 8, entries + (size_t)3 * HID * 8, A1, A2);
  layer_kernel<<<HID / 256, 256, 0, stream>>>(
      entries + (size_t)4 * HID * 8, entries + (size_t)5 * HID * 8, A2, A3);
  logits_kernel<<<HID / 32, 128, 0, stream>>>(A1, A2, A3, O0, O1, O2, out);
}